// Round 4
// baseline (298.339 us; speedup 1.0000x reference)
//
#include <hip/hip_runtime.h>
#include <stdint.h>
#include <math.h>

// MulHeadAttn on MI355X. B=2, C=1024, E=1024, head_dim(H)=16, n_heads(HD)=64.
// R12: single fused persistent kernel (1 dispatch instead of 4) with
// device-scope grid barriers between stages:
//   stage0 cast(fp32->bf16, Wq pre-scaled 0.25*log2e)
//   stage1 fused QKV bf16-MFMA GEMM (128x128 tile, global_load_lds dbuf)
//   stage2 MFMA flash attention (keys-split waves, exp2-domain softmax)
//   stage3 bf16-MFMA O-projection (64x128 tile)
// Co-residency for the spin barrier is guaranteed: grid=512=2 blocks/CU,
// LDS 49.4KB (2x <= 160KB), __launch_bounds__(256,2) caps VGPR at 256.

typedef __bf16   bf16x8 __attribute__((ext_vector_type(8)));
typedef float    f32x4  __attribute__((ext_vector_type(4)));

#define NBLK 512

__device__ __forceinline__ unsigned short f2bf(float f) {
    unsigned int u = __float_as_uint(f);
    u += 0x7FFFu + ((u >> 16) & 1u);         // round-to-nearest-even
    return (unsigned short)(u >> 16);
}

// pack two fp32 -> u32 of two bf16 (RNE), single VALU op
__device__ __forceinline__ unsigned int cvtpk(float lo, float hi) {
    unsigned int r;
    asm("v_cvt_pk_bf16_f32 %0, %1, %2" : "=v"(r) : "v"(lo), "v"(hi));
    return r;
}

// async global->LDS, 16 bytes per lane (dest = wave-uniform base + lane*16)
__device__ __forceinline__ void gl16(const unsigned short* g, unsigned short* l) {
    __builtin_amdgcn_global_load_lds(
        (const __attribute__((address_space(1))) unsigned int*)g,
        (__attribute__((address_space(3))) unsigned int*)l, 16, 0, 0);
}

// Device-scope grid barrier. Producer: release fence + device atomicAdd.
// Consumer: relaxed agent-scope polling loads (no RMW hammering) + acquire
// fence on exit. Safe because all NBLK blocks are co-resident (see header).
__device__ __forceinline__ void gridbar(unsigned int* cnt) {
    __syncthreads();
    if (threadIdx.x == 0) {
        __threadfence();                       // release: flush L1/L2 writes
        atomicAdd(cnt, 1u);                    // device-scope (m20)
        while (__hip_atomic_load(cnt, __ATOMIC_RELAXED,
                                 __HIP_MEMORY_SCOPE_AGENT) < NBLK)
            __builtin_amdgcn_s_sleep(4);
        __threadfence();                       // acquire: invalidate stale L1/L2
    }
    __syncthreads();
}

// ------------------------------------------------- stage 1: QKV GEMM ----
// 128x128 tile, BK=32, 4 waves x acc[4][4] of 16x16x32 MFMA.
// global_load_lds width-16, double-buffered, one barrier per K-step.
__device__ void dev_gemm128(int bx, int by, int bz, unsigned char* smem,
    const unsigned short* A,
    const unsigned short* B0, const unsigned short* B1, const unsigned short* B2,
    unsigned short* C0, unsigned short* C1, unsigned short* C2)
{
    const int K = 1024, N = 1024;
    const unsigned short* Bm = (bz == 0) ? B0 : (bz == 1) ? B1 : B2;
    unsigned short* Cm       = (bz == 0) ? C0 : (bz == 1) ? C1 : C2;

    unsigned short* As = (unsigned short*)smem;             // [2][128*32] 16 KB
    unsigned short* Bs = (unsigned short*)(smem + 16384);   // [2][128*32] 16 KB

    const int t    = threadIdx.x;
    const int lane = t & 63;
    const int w    = t >> 6;
    const int m0   = by * 128;
    const int n0   = bx * 128;
    const int wm   = (w & 1) * 64;
    const int wn   = (w >> 1) * 64;

    const int r0 = t >> 2;
    const int c0 = (t & 3) * 8;
    const unsigned short* Apa = A  + (size_t)(m0 + r0) * K + c0;
    const unsigned short* Apb = Apa + (size_t)64 * K;
    const unsigned short* Bpa = Bm + (size_t)(n0 + r0) * K + c0;
    const unsigned short* Bpb = Bpa + (size_t)64 * K;
    unsigned short* lA0 = As + w * 512;
    unsigned short* lA1 = As + 2048 + w * 512;
    unsigned short* lB0 = Bs + w * 512;
    unsigned short* lB1 = Bs + 2048 + w * 512;
    const int bufStr = 128 * 32;   // u16 elements per buffer

    f32x4 acc[4][4];
#pragma unroll
    for (int i = 0; i < 4; ++i)
#pragma unroll
        for (int j = 0; j < 4; ++j) acc[i][j] = (f32x4){0.f, 0.f, 0.f, 0.f};

    const int fm = lane & 15;
    const int kg = lane >> 4;

    gl16(Apa, lA0);
    gl16(Apb, lA1);
    gl16(Bpa, lB0);
    gl16(Bpb, lB1);

    int cur = 0;
    for (int k0 = 0; k0 < K; k0 += 32) {
        __syncthreads();   // drains vmcnt(0)+lgkmcnt(0): buf[cur] staged

        if (k0 + 32 < K) {
            const int nb = (cur ^ 1);
            gl16(Apa + k0 + 32, lA0 + nb * bufStr);
            gl16(Apb + k0 + 32, lA1 + nb * bufStr);
            gl16(Bpa + k0 + 32, lB0 + nb * bufStr);
            gl16(Bpb + k0 + 32, lB1 + nb * bufStr);
        }

        const unsigned short* Ab = As + cur * bufStr;
        const unsigned short* Bb = Bs + cur * bufStr;
        bf16x8 af[4], bfr[4];
#pragma unroll
        for (int im = 0; im < 4; ++im)
            af[im] = *(const bf16x8*)&Ab[(wm + im * 16 + fm) * 32 + kg * 8];
#pragma unroll
        for (int in = 0; in < 4; ++in)
            bfr[in] = *(const bf16x8*)&Bb[(wn + in * 16 + fm) * 32 + kg * 8];
#pragma unroll
        for (int im = 0; im < 4; ++im)
#pragma unroll
            for (int in = 0; in < 4; ++in)
                acc[im][in] = __builtin_amdgcn_mfma_f32_16x16x32_bf16(
                    af[im], bfr[in], acc[im][in], 0, 0, 0);

        cur ^= 1;
    }

#pragma unroll
    for (int im = 0; im < 4; ++im) {
#pragma unroll
        for (int in = 0; in < 4; ++in) {
            const int row = m0 + wm + im * 16 + kg * 4;
            const int col = n0 + wn + in * 16 + fm;
#pragma unroll
            for (int r = 0; r < 4; ++r)
                Cm[(size_t)(row + r) * N + col] = f2bf(acc[im][in][r]);
        }
    }
}

// ----------------------------------------------- stage 3: O-proj GEMM ----
// 64x128 tile (256 jobs keep more blocks busy than 128x128 would).
__device__ void dev_gemm64(int bx, int by, unsigned char* smem,
    const unsigned short* A, const unsigned short* Bm, float* Cm)
{
    const int K = 1024, N = 1024;
    unsigned short* As = (unsigned short*)smem;             // [2][64*32]   8 KB
    unsigned short* Bs = (unsigned short*)(smem + 8192);    // [2][128*32] 16 KB

    const int t    = threadIdx.x;
    const int lane = t & 63;
    const int w    = t >> 6;
    const int m0   = by * 64;
    const int n0   = bx * 128;
    const int wm   = (w & 1) * 32;
    const int wn   = (w >> 1) * 64;

    const int r0 = t >> 2;
    const int c0 = (t & 3) * 8;
    const unsigned short* Apa = A  + (size_t)(m0 + r0) * K + c0;
    const unsigned short* Bpa = Bm + (size_t)(n0 + r0) * K + c0;
    const unsigned short* Bpb = Bm + (size_t)(n0 + r0 + 64) * K + c0;
    unsigned short* ldsA  = As + w * 512;
    unsigned short* ldsB0 = Bs + w * 512;
    unsigned short* ldsB1 = Bs + 2048 + w * 512;
    const int bufStrA = 64 * 32;
    const int bufStrB = 128 * 32;

    f32x4 acc[2][4];
#pragma unroll
    for (int i = 0; i < 2; ++i)
#pragma unroll
        for (int j = 0; j < 4; ++j) acc[i][j] = (f32x4){0.f, 0.f, 0.f, 0.f};

    const int fm = lane & 15;
    const int kg = lane >> 4;

    gl16(Apa, ldsA);
    gl16(Bpa, ldsB0);
    gl16(Bpb, ldsB1);

    int cur = 0;
    for (int k0 = 0; k0 < K; k0 += 32) {
        __syncthreads();

        if (k0 + 32 < K) {
            const int nb = (cur ^ 1);
            gl16(Apa + k0 + 32, ldsA  + nb * bufStrA);
            gl16(Bpa + k0 + 32, ldsB0 + nb * bufStrB);
            gl16(Bpb + k0 + 32, ldsB1 + nb * bufStrB);
        }

        const unsigned short* Ab = As + cur * bufStrA;
        const unsigned short* Bb = Bs + cur * bufStrB;
        bf16x8 af[2], bfr[4];
#pragma unroll
        for (int im = 0; im < 2; ++im)
            af[im] = *(const bf16x8*)&Ab[(wm + im * 16 + fm) * 32 + kg * 8];
#pragma unroll
        for (int in = 0; in < 4; ++in)
            bfr[in] = *(const bf16x8*)&Bb[(wn + in * 16 + fm) * 32 + kg * 8];
#pragma unroll
        for (int im = 0; im < 2; ++im)
#pragma unroll
            for (int in = 0; in < 4; ++in)
                acc[im][in] = __builtin_amdgcn_mfma_f32_16x16x32_bf16(
                    af[im], bfr[in], acc[im][in], 0, 0, 0);

        cur ^= 1;
    }

#pragma unroll
    for (int im = 0; im < 2; ++im) {
#pragma unroll
        for (int in = 0; in < 4; ++in) {
            const int row = m0 + wm + im * 16 + kg * 4;
            const int col = n0 + wn + in * 16 + fm;
#pragma unroll
            for (int r = 0; r < 4; ++r)
                Cm[(size_t)(row + r) * N + col] = acc[im][in][r];
        }
    }
}

// ------------------------------------------------- stage 2: attention ----
// keys-split: one job = one (b,hd) x 128 q-rows; KV tile = 128 keys; wave
// wv owns keys [wv*32,wv*32+32) x ALL 128 q-rows. Q frags + O acc in regs;
// final 4-way cross-wave O/l reduction through LDS overlaid on K/P buffers.
#define KSTR  40    // K tile row stride (16 real d + 16 zero-pad + 8 pad)
#define VSTRD 136   // VsT row stride (128 keys + 8 pad)
#define PSTRD 136   // Ps row stride  (128 keys + 8 pad)

__device__ void dev_attn(int bx, int by, unsigned char* smem,
    const unsigned short* Qb, const unsigned short* Kb,
    const unsigned short* Vb, unsigned short* Ob)
{
    // Ks [128][40] 10240 B | VsT [16][136] 4352 B | Ps [128][136] 34816 B
    // Red overlay: float[4][128][17] = 34816 B (after final barrier)
    unsigned short* Ks  = (unsigned short*)smem;
    unsigned short* VsT = (unsigned short*)(smem + 10240);
    unsigned short* Ps  = (unsigned short*)(smem + 14592);
    float*          Red = (float*)smem;

    const int t    = threadIdx.x;
    const int lane = t & 63;
    const int wv   = t >> 6;
    const int fm   = lane & 15;
    const int kg   = lane >> 4;
    const size_t base = ((size_t)(by >> 6) << 20) + (size_t)(by & 63) * 16;
    const int q0 = bx * 128;
    const int wk = wv * 32;          // wave's key offset within tile

    __syncthreads();   // previous job's Red readers done before pad-zero

    // zero the K d-pad (cols 16..31); real cols rewritten per tile
    {
        const int row = t >> 1, seg = t & 1;
        *(uint4*)&Ks[row * KSTR + 16 + seg * 8] = make_uint4(0, 0, 0, 0);
    }

    // Q fragments (B-operand): row q0+m*16+fm, k=kg*8 (zero for kg>=2)
    union { uint4 u; bf16x8 h; } zz; zz.u = make_uint4(0, 0, 0, 0);
    bf16x8 aq[8];
#pragma unroll
    for (int m = 0; m < 8; ++m) {
        if (kg < 2)
            aq[m] = *(const bf16x8*)(Qb + base +
                     (size_t)(q0 + m * 16 + fm) * 1024 + kg * 8);
        else
            aq[m] = zz.h;
    }

    f32x4 oacc[8];
    float lp[8];
#pragma unroll
    for (int m = 0; m < 8; ++m) {
        oacc[m] = (f32x4){0.f, 0.f, 0.f, 0.f};
        lp[m] = 0.f;
    }

    for (int kt = 0; kt < 1024; kt += 128) {
        __syncthreads();
        // stage K (row-major, 16 real d) and V (transposed) — all 256 thr
        {
            const int row = t >> 1, seg = t & 1;
            *(uint4*)&Ks[row * KSTR + seg * 8] =
                *(const uint4*)(Kb + base + (size_t)(kt + row) * 1024 + seg * 8);
            uint4 v = *(const uint4*)(Vb + base + (size_t)(kt + row) * 1024 + seg * 8);
            const unsigned short* pv = (const unsigned short*)&v;
#pragma unroll
            for (int d = 0; d < 8; ++d)
                VsT[(seg * 8 + d) * VSTRD + row] = pv[d];
        }
        __syncthreads();

        // K fragments for THIS wave's 32 keys only
        const bf16x8 bk0 = *(const bf16x8*)&Ks[(wk + fm) * KSTR + kg * 8];
        const bf16x8 bk1 = *(const bf16x8*)&Ks[(wk + 16 + fm) * KSTR + kg * 8];

        // ---- transposed QK + exp2 + cvt_pk P-store (wave-local Ps rows)
#pragma unroll
        for (int m = 0; m < 8; ++m) {
            f32x4 s0 = __builtin_amdgcn_mfma_f32_16x16x32_bf16(
                bk0, aq[m], (f32x4){0.f, 0.f, 0.f, 0.f}, 0, 0, 0);
            f32x4 s1 = __builtin_amdgcn_mfma_f32_16x16x32_bf16(
                bk1, aq[m], (f32x4){0.f, 0.f, 0.f, 0.f}, 0, 0, 0);
            const float p0 = __builtin_amdgcn_exp2f(s0[0]);
            const float p1 = __builtin_amdgcn_exp2f(s0[1]);
            const float p2 = __builtin_amdgcn_exp2f(s0[2]);
            const float p3 = __builtin_amdgcn_exp2f(s0[3]);
            const float p4 = __builtin_amdgcn_exp2f(s1[0]);
            const float p5 = __builtin_amdgcn_exp2f(s1[1]);
            const float p6 = __builtin_amdgcn_exp2f(s1[2]);
            const float p7 = __builtin_amdgcn_exp2f(s1[3]);
            lp[m] += ((p0 + p1) + (p2 + p3)) + ((p4 + p5) + (p6 + p7));
            unsigned short* prow = &Ps[(m * 16 + fm) * PSTRD + wk];
            *(uint2*)&prow[kg * 4]      = make_uint2(cvtpk(p0, p1), cvtpk(p2, p3));
            *(uint2*)&prow[16 + kg * 4] = make_uint2(cvtpk(p4, p5), cvtpk(p6, p7));
        }

        // ---- PV over this wave's 32 keys: one k=32 MFMA per q-group
        const bf16x8 bv = *(const bf16x8*)&VsT[fm * VSTRD + wk + kg * 8];
#pragma unroll
        for (int m = 0; m < 8; ++m) {
            const bf16x8 ap = *(const bf16x8*)&Ps[(m * 16 + fm) * PSTRD + wk + kg * 8];
            oacc[m] = __builtin_amdgcn_mfma_f32_16x16x32_bf16(ap, bv, oacc[m], 0, 0, 0);
        }
    }

    // l: sum the 4 kg-group partials -> every lane holds l_wave[q=m*16+fm]
#pragma unroll
    for (int m = 0; m < 8; ++m) {
        lp[m] += __shfl_xor(lp[m], 16, 64);
        lp[m] += __shfl_xor(lp[m], 32, 64);
    }

    __syncthreads();   // all waves done with Ks/VsT/Ps -> overlay Red
#pragma unroll
    for (int m = 0; m < 8; ++m) {
#pragma unroll
        for (int r = 0; r < 4; ++r)
            Red[((wv * 128) + m * 16 + kg * 4 + r) * 17 + fm] = oacc[m][r];
        if (kg == 0)
            Red[((wv * 128) + m * 16 + fm) * 17 + 16] = lp[m];
    }
    __syncthreads();

    // wave wv finalizes q-rows [wv*32, wv*32+32)
#pragma unroll
    for (int mp = 0; mp < 2; ++mp) {
#pragma unroll
        for (int r = 0; r < 4; ++r) {
            const int q = wv * 32 + mp * 16 + kg * 4 + r;
            const float o = Red[q * 17 + fm]         + Red[(128 + q) * 17 + fm] +
                            Red[(256 + q) * 17 + fm] + Red[(384 + q) * 17 + fm];
            const float l = Red[q * 17 + 16]         + Red[(128 + q) * 17 + 16] +
                            Red[(256 + q) * 17 + 16] + Red[(384 + q) * 17 + 16];
            Ob[base + (size_t)(q0 + q) * 1024 + fm] = f2bf(o / l);
        }
    }
}

// --------------------------------------------------- fused mega-kernel ----
__global__ __launch_bounds__(256, 2) void fused_mha(
    const float* __restrict__ x,
    const float* __restrict__ Wq, const float* __restrict__ Wk,
    const float* __restrict__ Wv, const float* __restrict__ Wo,
    unsigned short* ws16, float* out, unsigned int* bars)
{
    __shared__ __align__(16) unsigned char smem[49408];
    const int t   = threadIdx.x;
    const int blk = blockIdx.x;

    const size_t MEG = 1048576;
    unsigned short* xb  = ws16;
    unsigned short* Wqb = ws16 + 2 * MEG;
    unsigned short* Wkb = ws16 + 3 * MEG;
    unsigned short* Wvb = ws16 + 4 * MEG;
    unsigned short* Wob = ws16 + 5 * MEG;
    unsigned short* Qb  = ws16 + 6 * MEG;
    unsigned short* Kb  = ws16 + 8 * MEG;
    unsigned short* Vb  = ws16 + 10 * MEG;
    unsigned short* Ob  = ws16 + 12 * MEG;

    // ---- stage 0: cast. 6144 jobs of 1024 fp32. z=0,1: x halves;
    // z=2: Wq scaled 0.25*log2e (softmax scale folded into exp2 domain).
    for (int j = blk; j < 6144; j += NBLK) {
        const int z = j >> 10;
        const float* src;
        unsigned short* dst;
        size_t off = 0;
        float sc = 1.f;
        if (z < 2)       { src = x;  dst = xb; off = (size_t)z << 20; }
        else if (z == 2) { src = Wq; dst = Wqb; sc = 0.36067376022224085f; }
        else if (z == 3) { src = Wk; dst = Wkb; }
        else if (z == 4) { src = Wv; dst = Wvb; }
        else             { src = Wo; dst = Wob; }
        const size_t i = off + ((size_t)(j & 1023) * 256 + t) * 4;
        const float4 v = *(const float4*)(src + i);
        *(ushort4*)(dst + i) = make_ushort4(f2bf(v.x * sc), f2bf(v.y * sc),
                                            f2bf(v.z * sc), f2bf(v.w * sc));
    }
    gridbar(bars + 0);

    // ---- stage 1: QKV GEMM. 384 jobs (8 n-tiles x 16 m-tiles x 3 mats).
    for (int j = blk; j < 384; j += NBLK)
        dev_gemm128(j & 7, (j >> 3) & 15, j >> 7, smem,
                    xb, Wqb, Wkb, Wvb, Qb, Kb, Vb);
    gridbar(bars + 1);

    // ---- stage 2: attention. 1024 jobs (8 q-tiles x 128 bh) -> 2/block.
    for (int j = blk; j < 1024; j += NBLK)
        dev_attn(j & 7, j >> 3, smem, Qb, Kb, Vb, Ob);
    gridbar(bars + 2);

    // ---- stage 3: O-projection. 256 jobs (8 n-tiles x 32 m-tiles).
    for (int j = blk; j < 256; j += NBLK)
        dev_gemm64(j & 7, j >> 3, smem, Ob, Wob, out);
}

// -------------------------------------------------------------- launch ----
extern "C" void kernel_launch(void* const* d_in, const int* in_sizes, int n_in,
                              void* d_out, int out_size, void* d_ws, size_t ws_size,
                              hipStream_t stream) {
    const float* x  = (const float*)d_in[0];
    const float* Wq = (const float*)d_in[1];
    const float* Wk = (const float*)d_in[2];
    const float* Wv = (const float*)d_in[3];
    const float* Wo = (const float*)d_in[4];
    float* out = (float*)d_out;

    const size_t MEG = 1048576;
    unsigned short* ws = (unsigned short*)d_ws;        // data arena: 28 MB
    unsigned int* bars = (unsigned int*)(ws + 24 * MEG); // counters @ 48 MB

    hipMemsetAsync(bars, 0, 64, stream);               // zero 3 barrier counters
    fused_mha<<<dim3(NBLK), dim3(256), 0, stream>>>(x, Wq, Wk, Wv, Wo, ws, out, bars);
}

// Round 5
// 162.540 us; speedup vs baseline: 1.8355x; 1.8355x over previous
//
#include <hip/hip_runtime.h>
#include <stdint.h>
#include <math.h>

// MulHeadAttn on MI355X. B=2, C=1024, E=1024, head_dim(H)=16, n_heads(HD)=64.
// cast(fp32->bf16, Wq pre-scaled 0.25*log2e) -> fused QKV bf16-MFMA GEMM
// (128x128 tile, global_load_lds dbuf) -> MFMA flash attention
// (R13: barrier-free k-loop — all LDS wave-private; K frags direct from
//  global; 37.9KB LDS -> 4 blocks/CU, exact single wave-of-grid)
// -> bf16-MFMA O-projection (64x128 tile kernel).

typedef __bf16   bf16x8 __attribute__((ext_vector_type(8)));
typedef float    f32x4  __attribute__((ext_vector_type(4)));

__device__ __forceinline__ unsigned short f2bf(float f) {
    unsigned int u = __float_as_uint(f);
    u += 0x7FFFu + ((u >> 16) & 1u);         // round-to-nearest-even
    return (unsigned short)(u >> 16);
}

// pack two fp32 -> u32 of two bf16 (RNE), single VALU op
__device__ __forceinline__ unsigned int cvtpk(float lo, float hi) {
    unsigned int r;
    asm("v_cvt_pk_bf16_f32 %0, %1, %2" : "=v"(r) : "v"(lo), "v"(hi));
    return r;
}

// async global->LDS, 16 bytes per lane (dest = wave-uniform base + lane*16)
__device__ __forceinline__ void gl16(const unsigned short* g, unsigned short* l) {
    __builtin_amdgcn_global_load_lds(
        (const __attribute__((address_space(1))) unsigned int*)g,
        (__attribute__((address_space(3))) unsigned int*)l, 16, 0, 0);
}

// ---------------------------------------------------------------- cast ----
// z=0,1: halves of x; z=2: Wq scaled 0.25*log2(e) (softmax scale folded into
// the exp2 domain); z=3..5: Wk, Wv, Wo.
__global__ __launch_bounds__(256) void cast_to_bf16(
    const float* __restrict__ x,
    const float* __restrict__ w0, const float* __restrict__ w1,
    const float* __restrict__ w2, const float* __restrict__ w3,
    unsigned short* __restrict__ xb,
    unsigned short* __restrict__ b0, unsigned short* __restrict__ b1,
    unsigned short* __restrict__ b2, unsigned short* __restrict__ b3)
{
    const int z = blockIdx.y;
    const float* src;
    unsigned short* dst;
    size_t off = 0;
    float sc = 1.f;
    if (z < 2)       { src = x;  dst = xb; off = (size_t)z << 20; }
    else if (z == 2) { src = w0; dst = b0; sc = 0.36067376022224085f; } // 0.25*log2e
    else if (z == 3) { src = w1; dst = b1; }
    else if (z == 4) { src = w2; dst = b2; }
    else             { src = w3; dst = b3; }
    const size_t i = off + ((size_t)blockIdx.x * 256 + threadIdx.x) * 4;
    const float4 v = *(const float4*)(src + i);
    *(ushort4*)(dst + i) = make_ushort4(f2bf(v.x * sc), f2bf(v.y * sc),
                                        f2bf(v.z * sc), f2bf(v.w * sc));
}

// ------------------------------------------------------- GEMM 128x128 ----
// QKV GEMM: 128x128 tile, BK=32, 4 waves each computing a 64x64 sub-tile
// via acc[4][4] of 16x16x32 MFMA. global_load_lds width-16, double-buffered.
__global__ __launch_bounds__(256) void gemm128_bt_mfma(
    const unsigned short* __restrict__ A,
    const unsigned short* __restrict__ B0, const unsigned short* __restrict__ B1,
    const unsigned short* __restrict__ B2,
    unsigned short* __restrict__ C0, unsigned short* __restrict__ C1,
    unsigned short* __restrict__ C2,
    int M, int N, int K)
{
    const unsigned short* Bm = (blockIdx.z == 0) ? B0 : (blockIdx.z == 1) ? B1 : B2;
    unsigned short* Cm       = (blockIdx.z == 0) ? C0 : (blockIdx.z == 1) ? C1 : C2;

    __shared__ __align__(16) unsigned short As[2][128 * 32];  // 16 KB
    __shared__ __align__(16) unsigned short Bs[2][128 * 32];  // 16 KB

    const int t    = threadIdx.x;
    const int lane = t & 63;
    const int w    = t >> 6;
    const int m0   = blockIdx.y * 128;
    const int n0   = blockIdx.x * 128;
    const int wm   = (w & 1) * 64;
    const int wn   = (w >> 1) * 64;

    const int r0 = t >> 2;
    const int c0 = (t & 3) * 8;
    const unsigned short* Apa = A  + (size_t)(m0 + r0) * K + c0;
    const unsigned short* Apb = Apa + (size_t)64 * K;
    const unsigned short* Bpa = Bm + (size_t)(n0 + r0) * K + c0;
    const unsigned short* Bpb = Bpa + (size_t)64 * K;
    unsigned short* lA0 = &As[0][w * 512];
    unsigned short* lA1 = &As[0][2048 + w * 512];
    unsigned short* lB0 = &Bs[0][w * 512];
    unsigned short* lB1 = &Bs[0][2048 + w * 512];
    const int bufStr = 128 * 32;

    f32x4 acc[4][4];
#pragma unroll
    for (int i = 0; i < 4; ++i)
#pragma unroll
        for (int j = 0; j < 4; ++j) acc[i][j] = (f32x4){0.f, 0.f, 0.f, 0.f};

    const int fm = lane & 15;
    const int kg = lane >> 4;

    gl16(Apa, lA0);
    gl16(Apb, lA1);
    gl16(Bpa, lB0);
    gl16(Bpb, lB1);

    int cur = 0;
    for (int k0 = 0; k0 < K; k0 += 32) {
        __syncthreads();

        if (k0 + 32 < K) {
            const int nb = (cur ^ 1);
            gl16(Apa + k0 + 32, lA0 + nb * bufStr);
            gl16(Apb + k0 + 32, lA1 + nb * bufStr);
            gl16(Bpa + k0 + 32, lB0 + nb * bufStr);
            gl16(Bpb + k0 + 32, lB1 + nb * bufStr);
        }

        const unsigned short* Ab = &As[cur][0];
        const unsigned short* Bb = &Bs[cur][0];
        bf16x8 af[4], bfr[4];
#pragma unroll
        for (int im = 0; im < 4; ++im)
            af[im] = *(const bf16x8*)&Ab[(wm + im * 16 + fm) * 32 + kg * 8];
#pragma unroll
        for (int in = 0; in < 4; ++in)
            bfr[in] = *(const bf16x8*)&Bb[(wn + in * 16 + fm) * 32 + kg * 8];
#pragma unroll
        for (int im = 0; im < 4; ++im)
#pragma unroll
            for (int in = 0; in < 4; ++in)
                acc[im][in] = __builtin_amdgcn_mfma_f32_16x16x32_bf16(
                    af[im], bfr[in], acc[im][in], 0, 0, 0);

        cur ^= 1;
    }

#pragma unroll
    for (int im = 0; im < 4; ++im) {
#pragma unroll
        for (int in = 0; in < 4; ++in) {
            const int row = m0 + wm + im * 16 + kg * 4;
            const int col = n0 + wn + in * 16 + fm;
#pragma unroll
            for (int r = 0; r < 4; ++r)
                Cm[(size_t)(row + r) * N + col] = f2bf(acc[im][in][r]);
        }
    }
}

// -------------------------------------------------------- GEMM 64x128 ----
// O-projection (256 blocks keep the grid full where 128x128 would halve it).
__global__ __launch_bounds__(256) void gemm_bt_mfma(
    const unsigned short* __restrict__ A,
    const unsigned short* __restrict__ B0, const unsigned short* __restrict__ B1,
    const unsigned short* __restrict__ B2,
    void* __restrict__ C0, void* __restrict__ C1, void* __restrict__ C2,
    int M, int N, int K, int bf16out)
{
    const unsigned short* Bm = (blockIdx.z == 0) ? B0 : (blockIdx.z == 1) ? B1 : B2;
    void* Cm                 = (blockIdx.z == 0) ? C0 : (blockIdx.z == 1) ? C1 : C2;

    __shared__ __align__(16) unsigned short As[2][64 * 32];   //  8 KB
    __shared__ __align__(16) unsigned short Bs[2][128 * 32];  // 16 KB

    const int t    = threadIdx.x;
    const int lane = t & 63;
    const int w    = t >> 6;
    const int m0   = blockIdx.y * 64;
    const int n0   = blockIdx.x * 128;
    const int wm   = (w & 1) * 32;
    const int wn   = (w >> 1) * 64;

    const int r0 = t >> 2;
    const int c0 = (t & 3) * 8;
    const unsigned short* Apa = A  + (size_t)(m0 + r0) * K + c0;
    const unsigned short* Bpa = Bm + (size_t)(n0 + r0) * K + c0;
    const unsigned short* Bpb = Bm + (size_t)(n0 + r0 + 64) * K + c0;
    unsigned short* ldsA  = &As[0][w * 512];
    unsigned short* ldsB0 = &Bs[0][w * 512];
    unsigned short* ldsB1 = &Bs[0][2048 + w * 512];
    const int bufStrA = 64 * 32;
    const int bufStrB = 128 * 32;

    f32x4 acc[2][4];
#pragma unroll
    for (int i = 0; i < 2; ++i)
#pragma unroll
        for (int j = 0; j < 4; ++j) acc[i][j] = (f32x4){0.f, 0.f, 0.f, 0.f};

    const int fm = lane & 15;
    const int kg = lane >> 4;

    gl16(Apa, ldsA);
    gl16(Bpa, ldsB0);
    gl16(Bpb, ldsB1);

    int cur = 0;
    for (int k0 = 0; k0 < K; k0 += 32) {
        __syncthreads();

        if (k0 + 32 < K) {
            const int nb = (cur ^ 1);
            gl16(Apa + k0 + 32, ldsA  + nb * bufStrA);
            gl16(Bpa + k0 + 32, ldsB0 + nb * bufStrB);
            gl16(Bpb + k0 + 32, ldsB1 + nb * bufStrB);
        }

        const unsigned short* Ab = &As[cur][0];
        const unsigned short* Bb = &Bs[cur][0];
        bf16x8 af[2], bfr[4];
#pragma unroll
        for (int im = 0; im < 2; ++im)
            af[im] = *(const bf16x8*)&Ab[(wm + im * 16 + fm) * 32 + kg * 8];
#pragma unroll
        for (int in = 0; in < 4; ++in)
            bfr[in] = *(const bf16x8*)&Bb[(wn + in * 16 + fm) * 32 + kg * 8];
#pragma unroll
        for (int im = 0; im < 2; ++im)
#pragma unroll
            for (int in = 0; in < 4; ++in)
                acc[im][in] = __builtin_amdgcn_mfma_f32_16x16x32_bf16(
                    af[im], bfr[in], acc[im][in], 0, 0, 0);

        cur ^= 1;
    }

#pragma unroll
    for (int im = 0; im < 2; ++im) {
#pragma unroll
        for (int in = 0; in < 4; ++in) {
            const int row = m0 + wm + im * 16 + kg * 4;
            const int col = n0 + wn + in * 16 + fm;
            if (bf16out) {
                unsigned short* cp = (unsigned short*)Cm;
#pragma unroll
                for (int r = 0; r < 4; ++r)
                    cp[(size_t)(row + r) * N + col] = f2bf(acc[im][in][r]);
            } else {
                float* cp = (float*)Cm;
#pragma unroll
                for (int r = 0; r < 4; ++r)
                    cp[(size_t)(row + r) * N + col] = acc[im][in][r];
            }
        }
    }
}

// ----------------------------------------------------------- attention ----
// R13 barrier-free keys-split: grid (8,128) = 1024 blocks = EXACTLY 4/CU.
// Block = one (b,hd) x 128 q-rows, 4 waves; wave wv owns keys
// [wv*32,wv*32+32) x ALL 128 q-rows across the whole k-loop.
// Every LDS region is WAVE-PRIVATE -> zero block barriers in the k-loop
// (in-order DS + compiler lgkmcnt give wave-internal cross-lane ordering).
// K fragments load DIRECT from global (per-lane 16B = exact A-frag layout;
// K tiles are L2-hot) — no Ks buffer, no pad-zeroing, no K staging.
// LDS 37.9 KB: VsT [4][16][40] + Ps [4][128][32]; Red overlay for the final
// cross-wave O/l reduction (2 block barriers total per job).
#define VSTRW 40    // per-wave VsT row stride (u16): 32 keys + 8 pad
#define PSTRW 32    // per-wave Ps  row stride (u16): 32 keys, 64B rows

__global__ __launch_bounds__(256, 4) void attn_mfma(
    const unsigned short* __restrict__ Qb, const unsigned short* __restrict__ Kb,
    const unsigned short* __restrict__ Vb, unsigned short* __restrict__ Ob)
{
    // VsT: 4 waves x [16][40] u16 = 5120 B | Ps: 4 x [128][32] u16 = 32768 B
    // Red overlay (whole smem after barrier): float[4][128][17] = 34816 B
    __shared__ __align__(16) unsigned char smem[37888];

    const int t    = threadIdx.x;
    const int lane = t & 63;
    const int wv   = t >> 6;
    const int fm   = lane & 15;
    const int kg   = lane >> 4;
    const int bh   = blockIdx.y;
    const size_t base = ((size_t)(bh >> 6) << 20) + (size_t)(bh & 63) * 16;
    const int q0 = blockIdx.x * 128;
    const int wk = wv * 32;          // wave's key offset within tile

    unsigned short* VsT = (unsigned short*)(smem + wv * 1280);
    unsigned short* Ps  = (unsigned short*)(smem + 5120 + wv * 8192);
    float*          Red = (float*)smem;

    // Q fragments (B-operand): row q0+m*16+fm, k=kg*8 (zero for kg>=2)
    union { uint4 u; bf16x8 h; } zz; zz.u = make_uint4(0, 0, 0, 0);
    bf16x8 aq[8];
#pragma unroll
    for (int m = 0; m < 8; ++m) {
        if (kg < 2)
            aq[m] = *(const bf16x8*)(Qb + base +
                     (size_t)(q0 + m * 16 + fm) * 1024 + kg * 8);
        else
            aq[m] = zz.h;
    }

    f32x4 oacc[8];
    float lp[8];
#pragma unroll
    for (int m = 0; m < 8; ++m) {
        oacc[m] = (f32x4){0.f, 0.f, 0.f, 0.f};
        lp[m] = 0.f;
    }

    for (int kt = 0; kt < 1024; kt += 128) {
        // ---- stage V (wave-private): lane covers one (key, d-half)
        {
            const int key = lane >> 1, half = lane & 1;
            const uint4 v = *(const uint4*)(Vb + base +
                             (size_t)(kt + wk + key) * 1024 + half * 8);
            const unsigned short* pv = (const unsigned short*)&v;
#pragma unroll
            for (int d = 0; d < 8; ++d)
                VsT[(half * 8 + d) * VSTRW + key] = pv[d];
        }

        // ---- K fragments DIRECT from global (kg>=2 = k-dim zero pad)
        bf16x8 bk0 = zz.h, bk1 = zz.h;
        if (kg < 2) {
            bk0 = *(const bf16x8*)(Kb + base +
                   (size_t)(kt + wk + fm) * 1024 + kg * 8);
            bk1 = *(const bf16x8*)(Kb + base +
                   (size_t)(kt + wk + 16 + fm) * 1024 + kg * 8);
        }

        // ---- transposed QK + exp2 + cvt_pk P-store (wave-private Ps)
#pragma unroll
        for (int m = 0; m < 8; ++m) {
            f32x4 s0 = __builtin_amdgcn_mfma_f32_16x16x32_bf16(
                bk0, aq[m], (f32x4){0.f, 0.f, 0.f, 0.f}, 0, 0, 0);
            f32x4 s1 = __builtin_amdgcn_mfma_f32_16x16x32_bf16(
                bk1, aq[m], (f32x4){0.f, 0.f, 0.f, 0.f}, 0, 0, 0);
            const float p0 = __builtin_amdgcn_exp2f(s0[0]);
            const float p1 = __builtin_amdgcn_exp2f(s0[1]);
            const float p2 = __builtin_amdgcn_exp2f(s0[2]);
            const float p3 = __builtin_amdgcn_exp2f(s0[3]);
            const float p4 = __builtin_amdgcn_exp2f(s1[0]);
            const float p5 = __builtin_amdgcn_exp2f(s1[1]);
            const float p6 = __builtin_amdgcn_exp2f(s1[2]);
            const float p7 = __builtin_amdgcn_exp2f(s1[3]);
            lp[m] += ((p0 + p1) + (p2 + p3)) + ((p4 + p5) + (p6 + p7));
            unsigned short* prow = Ps + (m * 16 + fm) * PSTRW;
            *(uint2*)&prow[kg * 4]      = make_uint2(cvtpk(p0, p1), cvtpk(p2, p3));
            *(uint2*)&prow[16 + kg * 4] = make_uint2(cvtpk(p4, p5), cvtpk(p6, p7));
        }

        // ---- PV over this wave's 32 keys (wave-private reads)
        const bf16x8 bv = *(const bf16x8*)&VsT[fm * VSTRW + kg * 8];
#pragma unroll
        for (int m = 0; m < 8; ++m) {
            const bf16x8 ap = *(const bf16x8*)&Ps[(m * 16 + fm) * PSTRW + kg * 8];
            oacc[m] = __builtin_amdgcn_mfma_f32_16x16x32_bf16(ap, bv, oacc[m], 0, 0, 0);
        }
    }

    // l: sum the 4 kg-group partials -> every lane holds l_wave[q=m*16+fm]
#pragma unroll
    for (int m = 0; m < 8; ++m) {
        lp[m] += __shfl_xor(lp[m], 16, 64);
        lp[m] += __shfl_xor(lp[m], 32, 64);
    }

    __syncthreads();   // all waves done with VsT/Ps -> overlay Red
#pragma unroll
    for (int m = 0; m < 8; ++m) {
#pragma unroll
        for (int r = 0; r < 4; ++r)
            Red[((wv * 128) + m * 16 + kg * 4 + r) * 17 + fm] = oacc[m][r];
        if (kg == 0)
            Red[((wv * 128) + m * 16 + fm) * 17 + 16] = lp[m];
    }
    __syncthreads();

    // wave wv finalizes q-rows [wv*32, wv*32+32)
#pragma unroll
    for (int mp = 0; mp < 2; ++mp) {
#pragma unroll
        for (int r = 0; r < 4; ++r) {
            const int q = wv * 32 + mp * 16 + kg * 4 + r;
            const float o = Red[q * 17 + fm]         + Red[(128 + q) * 17 + fm] +
                            Red[(256 + q) * 17 + fm] + Red[(384 + q) * 17 + fm];
            const float l = Red[q * 17 + 16]         + Red[(128 + q) * 17 + 16] +
                            Red[(256 + q) * 17 + 16] + Red[(384 + q) * 17 + 16];
            Ob[base + (size_t)(q0 + q) * 1024 + fm] = f2bf(o / l);
        }
    }
}

// -------------------------------------------------------------- launch ----
extern "C" void kernel_launch(void* const* d_in, const int* in_sizes, int n_in,
                              void* d_out, int out_size, void* d_ws, size_t ws_size,
                              hipStream_t stream) {
    const float* x  = (const float*)d_in[0];
    const float* Wq = (const float*)d_in[1];
    const float* Wk = (const float*)d_in[2];
    const float* Wv = (const float*)d_in[3];
    const float* Wo = (const float*)d_in[4];
    float* out = (float*)d_out;

    const int M = 2048, N = 1024, Kd = 1024;
    const size_t MEG = 1048576;
    unsigned short* ws = (unsigned short*)d_ws;   // 28 MB high-water
    unsigned short* xb  = ws;
    unsigned short* Wqb = ws + 2 * MEG;
    unsigned short* Wkb = ws + 3 * MEG;
    unsigned short* Wvb = ws + 4 * MEG;
    unsigned short* Wob = ws + 5 * MEG;
    unsigned short* Qb  = ws + 6 * MEG;
    unsigned short* Kb  = ws + 8 * MEG;
    unsigned short* Vb  = ws + 10 * MEG;
    unsigned short* Ob  = ws + 12 * MEG;

    dim3 gc(1024, 6, 1);
    cast_to_bf16<<<gc, 256, 0, stream>>>(x, Wq, Wk, Wv, Wo, xb, Wqb, Wkb, Wvb, Wob);

    dim3 g1(N / 128, M / 128, 3);
    gemm128_bt_mfma<<<g1, 256, 0, stream>>>(xb, Wqb, Wkb, Wvb, Qb, Kb, Vb, M, N, Kd);

    dim3 g2(8, 128, 1);
    attn_mfma<<<g2, 256, 0, stream>>>(Qb, Kb, Vb, Ob);

    dim3 g3(N / 128, M / 64, 1);
    gemm_bt_mfma<<<g3, 256, 0, stream>>>(Ob, Wob, Wob, Wob, out, out, out, M, N, Kd, 0);
}

// Round 8
// 143.799 us; speedup vs baseline: 2.0747x; 1.1303x over previous
//
#include <hip/hip_runtime.h>
#include <stdint.h>
#include <math.h>

// MulHeadAttn on MI355X. B=2, C=1024, E=1024, head_dim(H)=16, n_heads(HD)=64.
// cast(fp32->bf16, Wq pre-scaled 0.25*log2e) -> fused QKV bf16-MFMA GEMM
// (128x128 tile, global_load_lds dbuf) -> MFMA flash attention
// (R16: P-in-register via permuted key axis — QK output IS the PV A-frag.
//  vs R14: PV A-frag built with plain (__bf16) casts instead of inline-asm
//  v_cvt_pk feeding MFMA directly — inline-asm VGPR defs are opaque to the
//  hazard recognizer; R14 NaN'd, R13 passed with cvtpk->ds_write only)
// -> bf16-MFMA O-projection (64x128 tile kernel).

typedef __bf16   bf16x8 __attribute__((ext_vector_type(8)));
typedef float    f32x4  __attribute__((ext_vector_type(4)));

__device__ __forceinline__ unsigned short f2bf(float f) {
    unsigned int u = __float_as_uint(f);
    u += 0x7FFFu + ((u >> 16) & 1u);         // round-to-nearest-even
    return (unsigned short)(u >> 16);
}

// async global->LDS, 16 bytes per lane (dest = wave-uniform base + lane*16)
__device__ __forceinline__ void gl16(const unsigned short* g, unsigned short* l) {
    __builtin_amdgcn_global_load_lds(
        (const __attribute__((address_space(1))) unsigned int*)g,
        (__attribute__((address_space(3))) unsigned int*)l, 16, 0, 0);
}

// ---------------------------------------------------------------- cast ----
// z=0,1: halves of x; z=2: Wq scaled 0.25*log2(e) (softmax scale folded into
// the exp2 domain); z=3..5: Wk, Wv, Wo.
__global__ __launch_bounds__(256) void cast_to_bf16(
    const float* __restrict__ x,
    const float* __restrict__ w0, const float* __restrict__ w1,
    const float* __restrict__ w2, const float* __restrict__ w3,
    unsigned short* __restrict__ xb,
    unsigned short* __restrict__ b0, unsigned short* __restrict__ b1,
    unsigned short* __restrict__ b2, unsigned short* __restrict__ b3)
{
    const int z = blockIdx.y;
    const float* src;
    unsigned short* dst;
    size_t off = 0;
    float sc = 1.f;
    if (z < 2)       { src = x;  dst = xb; off = (size_t)z << 20; }
    else if (z == 2) { src = w0; dst = b0; sc = 0.36067376022224085f; } // 0.25*log2e
    else if (z == 3) { src = w1; dst = b1; }
    else if (z == 4) { src = w2; dst = b2; }
    else             { src = w3; dst = b3; }
    const size_t i = off + ((size_t)blockIdx.x * 256 + threadIdx.x) * 4;
    const float4 v = *(const float4*)(src + i);
    *(ushort4*)(dst + i) = make_ushort4(f2bf(v.x * sc), f2bf(v.y * sc),
                                        f2bf(v.z * sc), f2bf(v.w * sc));
}

// ------------------------------------------------------- GEMM 128x128 ----
// QKV GEMM: 128x128 tile, BK=32, 4 waves each computing a 64x64 sub-tile
// via acc[4][4] of 16x16x32 MFMA. global_load_lds width-16, double-buffered.
__global__ __launch_bounds__(256) void gemm128_bt_mfma(
    const unsigned short* __restrict__ A,
    const unsigned short* __restrict__ B0, const unsigned short* __restrict__ B1,
    const unsigned short* __restrict__ B2,
    unsigned short* __restrict__ C0, unsigned short* __restrict__ C1,
    unsigned short* __restrict__ C2,
    int M, int N, int K)
{
    const unsigned short* Bm = (blockIdx.z == 0) ? B0 : (blockIdx.z == 1) ? B1 : B2;
    unsigned short* Cm       = (blockIdx.z == 0) ? C0 : (blockIdx.z == 1) ? C1 : C2;

    __shared__ __align__(16) unsigned short As[2][128 * 32];  // 16 KB
    __shared__ __align__(16) unsigned short Bs[2][128 * 32];  // 16 KB

    const int t    = threadIdx.x;
    const int lane = t & 63;
    const int w    = t >> 6;
    const int m0   = blockIdx.y * 128;
    const int n0   = blockIdx.x * 128;
    const int wm   = (w & 1) * 64;
    const int wn   = (w >> 1) * 64;

    const int r0 = t >> 2;
    const int c0 = (t & 3) * 8;
    const unsigned short* Apa = A  + (size_t)(m0 + r0) * K + c0;
    const unsigned short* Apb = Apa + (size_t)64 * K;
    const unsigned short* Bpa = Bm + (size_t)(n0 + r0) * K + c0;
    const unsigned short* Bpb = Bpa + (size_t)64 * K;
    unsigned short* lA0 = &As[0][w * 512];
    unsigned short* lA1 = &As[0][2048 + w * 512];
    unsigned short* lB0 = &Bs[0][w * 512];
    unsigned short* lB1 = &Bs[0][2048 + w * 512];
    const int bufStr = 128 * 32;

    f32x4 acc[4][4];
#pragma unroll
    for (int i = 0; i < 4; ++i)
#pragma unroll
        for (int j = 0; j < 4; ++j) acc[i][j] = (f32x4){0.f, 0.f, 0.f, 0.f};

    const int fm = lane & 15;
    const int kg = lane >> 4;

    gl16(Apa, lA0);
    gl16(Apb, lA1);
    gl16(Bpa, lB0);
    gl16(Bpb, lB1);

    int cur = 0;
    for (int k0 = 0; k0 < K; k0 += 32) {
        __syncthreads();

        if (k0 + 32 < K) {
            const int nb = (cur ^ 1);
            gl16(Apa + k0 + 32, lA0 + nb * bufStr);
            gl16(Apb + k0 + 32, lA1 + nb * bufStr);
            gl16(Bpa + k0 + 32, lB0 + nb * bufStr);
            gl16(Bpb + k0 + 32, lB1 + nb * bufStr);
        }

        const unsigned short* Ab = &As[cur][0];
        const unsigned short* Bb = &Bs[cur][0];
        bf16x8 af[4], bfr[4];
#pragma unroll
        for (int im = 0; im < 4; ++im)
            af[im] = *(const bf16x8*)&Ab[(wm + im * 16 + fm) * 32 + kg * 8];
#pragma unroll
        for (int in = 0; in < 4; ++in)
            bfr[in] = *(const bf16x8*)&Bb[(wn + in * 16 + fm) * 32 + kg * 8];
#pragma unroll
        for (int im = 0; im < 4; ++im)
#pragma unroll
            for (int in = 0; in < 4; ++in)
                acc[im][in] = __builtin_amdgcn_mfma_f32_16x16x32_bf16(
                    af[im], bfr[in], acc[im][in], 0, 0, 0);

        cur ^= 1;
    }

#pragma unroll
    for (int im = 0; im < 4; ++im) {
#pragma unroll
        for (int in = 0; in < 4; ++in) {
            const int row = m0 + wm + im * 16 + kg * 4;
            const int col = n0 + wn + in * 16 + fm;
#pragma unroll
            for (int r = 0; r < 4; ++r)
                Cm[(size_t)(row + r) * N + col] = f2bf(acc[im][in][r]);
        }
    }
}

// -------------------------------------------------------- GEMM 64x128 ----
// O-projection (256 blocks keep the grid full where 128x128 would halve it).
__global__ __launch_bounds__(256) void gemm_bt_mfma(
    const unsigned short* __restrict__ A,
    const unsigned short* __restrict__ B0, const unsigned short* __restrict__ B1,
    const unsigned short* __restrict__ B2,
    void* __restrict__ C0, void* __restrict__ C1, void* __restrict__ C2,
    int M, int N, int K, int bf16out)
{
    const unsigned short* Bm = (blockIdx.z == 0) ? B0 : (blockIdx.z == 1) ? B1 : B2;
    void* Cm                 = (blockIdx.z == 0) ? C0 : (blockIdx.z == 1) ? C1 : C2;

    __shared__ __align__(16) unsigned short As[2][64 * 32];   //  8 KB
    __shared__ __align__(16) unsigned short Bs[2][128 * 32];  // 16 KB

    const int t    = threadIdx.x;
    const int lane = t & 63;
    const int w    = t >> 6;
    const int m0   = blockIdx.y * 64;
    const int n0   = blockIdx.x * 128;
    const int wm   = (w & 1) * 32;
    const int wn   = (w >> 1) * 64;

    const int r0 = t >> 2;
    const int c0 = (t & 3) * 8;
    const unsigned short* Apa = A  + (size_t)(m0 + r0) * K + c0;
    const unsigned short* Bpa = Bm + (size_t)(n0 + r0) * K + c0;
    const unsigned short* Bpb = Bm + (size_t)(n0 + r0 + 64) * K + c0;
    unsigned short* ldsA  = &As[0][w * 512];
    unsigned short* ldsB0 = &Bs[0][w * 512];
    unsigned short* ldsB1 = &Bs[0][2048 + w * 512];
    const int bufStrA = 64 * 32;
    const int bufStrB = 128 * 32;

    f32x4 acc[2][4];
#pragma unroll
    for (int i = 0; i < 2; ++i)
#pragma unroll
        for (int j = 0; j < 4; ++j) acc[i][j] = (f32x4){0.f, 0.f, 0.f, 0.f};

    const int fm = lane & 15;
    const int kg = lane >> 4;

    gl16(Apa, ldsA);
    gl16(Bpa, ldsB0);
    gl16(Bpb, ldsB1);

    int cur = 0;
    for (int k0 = 0; k0 < K; k0 += 32) {
        __syncthreads();

        if (k0 + 32 < K) {
            const int nb = (cur ^ 1);
            gl16(Apa + k0 + 32, ldsA  + nb * bufStrA);
            gl16(Bpa + k0 + 32, ldsB0 + nb * bufStrB);
            gl16(Bpb + k0 + 32, ldsB1 + nb * bufStrB);
        }

        const unsigned short* Ab = &As[cur][0];
        const unsigned short* Bb = &Bs[cur][0];
        bf16x8 af[2], bfr[4];
#pragma unroll
        for (int im = 0; im < 2; ++im)
            af[im] = *(const bf16x8*)&Ab[(wm + im * 16 + fm) * 32 + kg * 8];
#pragma unroll
        for (int in = 0; in < 4; ++in)
            bfr[in] = *(const bf16x8*)&Bb[(wn + in * 16 + fm) * 32 + kg * 8];
#pragma unroll
        for (int im = 0; im < 2; ++im)
#pragma unroll
            for (int in = 0; in < 4; ++in)
                acc[im][in] = __builtin_amdgcn_mfma_f32_16x16x32_bf16(
                    af[im], bfr[in], acc[im][in], 0, 0, 0);

        cur ^= 1;
    }

#pragma unroll
    for (int im = 0; im < 2; ++im) {
#pragma unroll
        for (int in = 0; in < 4; ++in) {
            const int row = m0 + wm + im * 16 + kg * 4;
            const int col = n0 + wn + in * 16 + fm;
            if (bf16out) {
                unsigned short* cp = (unsigned short*)Cm;
#pragma unroll
                for (int r = 0; r < 4; ++r)
                    cp[(size_t)(row + r) * N + col] = f2bf(acc[im][in][r]);
            } else {
                float* cp = (float*)Cm;
#pragma unroll
                for (int r = 0; r < 4; ++r)
                    cp[(size_t)(row + r) * N + col] = acc[im][in][r];
            }
        }
    }
}

// ----------------------------------------------------------- attention ----
// R16: keys-split (wave wv owns keys [wv*32,wv*32+32) x all 128 q), grid
// (8,128) = 1024 blocks = 4/CU, barrier-free k-loop (all LDS wave-private).
//
// P-IN-REGISTER: define the PV k-slot -> key permutation as
//   slot c (c=0..31): key = (c&7)<4 ? (c>>3)*4+(c&7) : 16+(c>>3)*4+(c&7)-4
// Then lane (fm,kg)'s QK outputs {keys 4kg..4kg+3, 16+4kg..16+4kg+3} are
// EXACTLY its PV A-frag slots 8kg..8kg+7 — P never touches LDS. V^T is
// staged with the same permuted column order (contraction is invariant
// under a shared permutation of the summation axis).
//
// PV A-frag built with plain (__bf16) casts — compiler emits its own
// v_cvt_pk_bf16_f32 WITH hazard-correct scheduling into the MFMA (R14's
// inline-asm def fed the MFMA stale registers -> NaN).
//
// LDS (per wave, conflict-minimal): Ks [32 keys][40 u16] (80B rows), VsT
// [16 d][72 u16] (144B rows). K staged coalesced (2 lanes x 16B per row).
#define KROWS 40    // Ks row stride (u16): 16 real d + 24 pad (80 B)
#define VROWS 72    // VsT row stride (u16): 32 perm cols + 40 pad (144 B)

__global__ __launch_bounds__(256, 4) void attn_mfma(
    const unsigned short* __restrict__ Qb, const unsigned short* __restrict__ Kb,
    const unsigned short* __restrict__ Vb, unsigned short* __restrict__ Ob)
{
    // per-wave: Ks 2560 B @ wv*2560 | VsT 2304 B @ 10240+wv*2304 (19456 B live)
    // Red overlay (after final barrier): float[512][17] = 34816 B
    __shared__ __align__(16) unsigned char smem[34816];

    const int t    = threadIdx.x;
    const int lane = t & 63;
    const int wv   = t >> 6;
    const int fm   = lane & 15;
    const int kg   = lane >> 4;
    const int bh   = blockIdx.y;
    const size_t base = ((size_t)(bh >> 6) << 20) + (size_t)(bh & 63) * 16;
    const int q0 = blockIdx.x * 128;
    const int wk = wv * 32;          // wave's key offset within tile

    unsigned short* Ks  = (unsigned short*)(smem + wv * 2560);
    unsigned short* VsT = (unsigned short*)(smem + 10240 + wv * 2304);
    float*          Red = (float*)smem;

    // staging roles: lane covers (key2 = lane>>1, half = lane&1)
    const int key2 = lane >> 1, half = lane & 1;
    // permuted V column for key2: slot where PV expects this key
    const int vcol = ((key2 & 15) >> 2) * 8 + (key2 & 3) + ((key2 >> 4) << 2);

    // Q fragments (B-operand): row q0+m*16+fm, k=kg*8 (zero for kg>=2)
    union { uint4 u; bf16x8 h; } zz; zz.u = make_uint4(0, 0, 0, 0);
    bf16x8 aq[8];
#pragma unroll
    for (int m = 0; m < 8; ++m) {
        if (kg < 2)
            aq[m] = *(const bf16x8*)(Qb + base +
                     (size_t)(q0 + m * 16 + fm) * 1024 + kg * 8);
        else
            aq[m] = zz.h;
    }

    f32x4 oacc[8];
    float lp[8];
#pragma unroll
    for (int m = 0; m < 8; ++m) {
        oacc[m] = (f32x4){0.f, 0.f, 0.f, 0.f};
        lp[m] = 0.f;
    }

    for (int kt = 0; kt < 1024; kt += 128) {
        // ---- stage K (coalesced 16B, b128 LDS write) + V (perm scatter)
        {
            const uint4 kd = *(const uint4*)(Kb + base +
                              (size_t)(kt + wk + key2) * 1024 + half * 8);
            *(uint4*)&Ks[key2 * KROWS + half * 8] = kd;
            const uint4 vd = *(const uint4*)(Vb + base +
                              (size_t)(kt + wk + key2) * 1024 + half * 8);
            const unsigned short* pv = (const unsigned short*)&vd;
#pragma unroll
            for (int d = 0; d < 8; ++d)
                VsT[(half * 8 + d) * VROWS + vcol] = pv[d];
        }

        // ---- K fragments (A-operand) from LDS: row fm / 16+fm, k=kg*8
        bf16x8 bk0 = zz.h, bk1 = zz.h;
        if (kg < 2) {
            bk0 = *(const bf16x8*)&Ks[fm * KROWS + kg * 8];
            bk1 = *(const bf16x8*)&Ks[(16 + fm) * KROWS + kg * 8];
        }

        // ---- V fragment (B-operand, perm cols): row d=fm, slots kg*8..+8
        const bf16x8 bv = *(const bf16x8*)&VsT[fm * VROWS + kg * 8];

        // ---- QK -> exp2 -> in-register P -> PV (all per-lane)
#pragma unroll
        for (int m = 0; m < 8; ++m) {
            f32x4 s0 = __builtin_amdgcn_mfma_f32_16x16x32_bf16(
                bk0, aq[m], (f32x4){0.f, 0.f, 0.f, 0.f}, 0, 0, 0);
            f32x4 s1 = __builtin_amdgcn_mfma_f32_16x16x32_bf16(
                bk1, aq[m], (f32x4){0.f, 0.f, 0.f, 0.f}, 0, 0, 0);
            const float p0 = __builtin_amdgcn_exp2f(s0[0]);
            const float p1 = __builtin_amdgcn_exp2f(s0[1]);
            const float p2 = __builtin_amdgcn_exp2f(s0[2]);
            const float p3 = __builtin_amdgcn_exp2f(s0[3]);
            const float p4 = __builtin_amdgcn_exp2f(s1[0]);
            const float p5 = __builtin_amdgcn_exp2f(s1[1]);
            const float p6 = __builtin_amdgcn_exp2f(s1[2]);
            const float p7 = __builtin_amdgcn_exp2f(s1[3]);
            lp[m] += ((p0 + p1) + (p2 + p3)) + ((p4 + p5) + (p6 + p7));
            bf16x8 aph;
            aph[0] = (__bf16)p0; aph[1] = (__bf16)p1;
            aph[2] = (__bf16)p2; aph[3] = (__bf16)p3;
            aph[4] = (__bf16)p4; aph[5] = (__bf16)p5;
            aph[6] = (__bf16)p6; aph[7] = (__bf16)p7;
            oacc[m] = __builtin_amdgcn_mfma_f32_16x16x32_bf16(
                aph, bv, oacc[m], 0, 0, 0);
        }
    }

    // l: sum the 4 kg-group partials -> every lane holds l_wave[q=m*16+fm]
#pragma unroll
    for (int m = 0; m < 8; ++m) {
        lp[m] += __shfl_xor(lp[m], 16, 64);
        lp[m] += __shfl_xor(lp[m], 32, 64);
    }

    __syncthreads();   // all waves done with Ks/VsT -> overlay Red
#pragma unroll
    for (int m = 0; m < 8; ++m) {
#pragma unroll
        for (int r = 0; r < 4; ++r)
            Red[((wv * 128) + m * 16 + kg * 4 + r) * 17 + fm] = oacc[m][r];
        if (kg == 0)
            Red[((wv * 128) + m * 16 + fm) * 17 + 16] = lp[m];
    }
    __syncthreads();

    // wave wv finalizes q-rows [wv*32, wv*32+32)
#pragma unroll
    for (int mp = 0; mp < 2; ++mp) {
#pragma unroll
        for (int r = 0; r < 4; ++r) {
            const int q = wv * 32 + mp * 16 + kg * 4 + r;
            const float o = Red[q * 17 + fm]         + Red[(128 + q) * 17 + fm] +
                            Red[(256 + q) * 17 + fm] + Red[(384 + q) * 17 + fm];
            const float l = Red[q * 17 + 16]         + Red[(128 + q) * 17 + 16] +
                            Red[(256 + q) * 17 + 16] + Red[(384 + q) * 17 + 16];
            Ob[base + (size_t)(q0 + q) * 1024 + fm] = f2bf(o / l);
        }
    }
}

// -------------------------------------------------------------- launch ----
extern "C" void kernel_launch(void* const* d_in, const int* in_sizes, int n_in,
                              void* d_out, int out_size, void* d_ws, size_t ws_size,
                              hipStream_t stream) {
    const float* x  = (const float*)d_in[0];
    const float* Wq = (const float*)d_in[1];
    const float* Wk = (const float*)d_in[2];
    const float* Wv = (const float*)d_in[3];
    const float* Wo = (const float*)d_in[4];
    float* out = (float*)d_out;

    const int M = 2048, N = 1024, Kd = 1024;
    const size_t MEG = 1048576;
    unsigned short* ws = (unsigned short*)d_ws;   // 28 MB high-water
    unsigned short* xb  = ws;
    unsigned short* Wqb = ws + 2 * MEG;
    unsigned short* Wkb = ws + 3 * MEG;
    unsigned short* Wvb = ws + 4 * MEG;
    unsigned short* Wob = ws + 5 * MEG;
    unsigned short* Qb  = ws + 6 * MEG;
    unsigned short* Kb  = ws + 8 * MEG;
    unsigned short* Vb  = ws + 10 * MEG;
    unsigned short* Ob  = ws + 12 * MEG;

    dim3 gc(1024, 6, 1);
    cast_to_bf16<<<gc, 256, 0, stream>>>(x, Wq, Wk, Wv, Wo, xb, Wqb, Wkb, Wvb, Wob);

    dim3 g1(N / 128, M / 128, 3);
    gemm128_bt_mfma<<<g1, 256, 0, stream>>>(xb, Wqb, Wkb, Wvb, Qb, Kb, Vb, M, N, Kd);

    dim3 g2(8, 128, 1);
    attn_mfma<<<g2, 256, 0, stream>>>(Qb, Kb, Vb, Ob);

    dim3 g3(N / 128, M / 64, 1);
    gemm_bt_mfma<<<g3, 256, 0, stream>>>(Ob, Wob, Wob, Wob, out, out, out, M, N, Kd, 0);
}